// Round 3
// baseline (44126.883 us; speedup 1.0000x reference)
//
#include <hip/hip_runtime.h>
#include <math.h>

#define NBLK 256
#define NTHR 512
#define HB 64      // batches per half
#define B_ 128
#define T_ 512
#define U_ 128
#define N_ 80
#define H_ 512
#define M_ 10
#define KTOT 595   // K order: [h 0..511][w 0..79][x 0..2]
#define NBUF 6

typedef __attribute__((address_space(1))) const unsigned int* gp1_t;
typedef __attribute__((address_space(3))) unsigned int* lp3_t;
// width-16 global->LDS DMA: lane i reads gptr + i*16, writes ldsbase + i*16
#define GLOAD16(gp, lp) __builtin_amdgcn_global_load_lds((gp1_t)(gp), (lp3_t)(lp), 16, 0, 0)

// dynamic-LDS float offsets
#define OFF_WL    0                    // 9520
#define OFF_BUF   9520                 // 6*2048 = 12288
#define OFF_ZBUF  21808                // 64*20 = 1280
#define OFF_HCOL  23088                // 512
#define OFF_WFL   23600                // 132 (16B aligned)
#define OFF_YL    23732                // 32
#define OFF_KAPL  23764                // 16
#define OFF_BDL   23780                // 32
#define OFF_BIASL 23812                // 16
#define OFF_CST   23828                // 256
#define SMEM_FLOATS 24084
#define SMEM_BYTES  (SMEM_FLOATS * 4)

__device__ __forceinline__ unsigned sum8(const unsigned* base) {
    unsigned s = 0;
    #pragma unroll
    for (int g = 0; g < 8; ++g)
        s += __hip_atomic_load(&base[g * 16], __ATOMIC_RELAXED, __HIP_MEMORY_SCOPE_AGENT);
    return s;
}
__device__ __forceinline__ void wait_sum8(const unsigned* base, unsigned target) {
    while (sum8(base) < target) __builtin_amdgcn_s_sleep(1);
}

__global__ __launch_bounds__(NTHR, 1) void rnn_kernel(
    const float* __restrict__ strokes, const float* __restrict__ trans,
    const float* __restrict__ Wx, const float* __restrict__ Wh,
    const float* __restrict__ bias, const float* __restrict__ Wd,
    const float* __restrict__ bd, float* __restrict__ out,
    float* __restrict__ hbuf, float* __restrict__ wbufT, float* __restrict__ hT,
    float* __restrict__ WdT, float* __restrict__ transT, unsigned* __restrict__ cnt) {

    extern __shared__ float smem[];
    float* Wl    = smem + OFF_WL;
    float* bufs  = smem + OFF_BUF;
    float* zbuf  = smem + OFF_ZBUF;
    float* hcol  = smem + OFF_HCOL;
    float* wfl   = smem + OFF_WFL;
    float* yl    = smem + OFF_YL;
    float* kapl  = smem + OFF_KAPL;
    float* bdl   = smem + OFF_BDL;
    float* biasl = smem + OFF_BIASL;
    float* cst   = smem + OFF_CST;
    __shared__ unsigned flags[NBUF];
    __shared__ unsigned done[4];
    __shared__ unsigned cbar;

    const int tid  = threadIdx.x;
    const int bid  = blockIdx.x;
    const int half = bid >> 7;
    const int hs   = bid & 127;          // h-units hs*4..hs*4+3
    const int lane = tid & 63;
    const int w8   = tid >> 6;

    unsigned* hcnt = cnt + half * 128;          // 8 groups x stride16
    unsigned* wcnt = cnt + 256 + half * 128;
    float* wT_half = wbufT + half * (N_ * HB);

    // ---------------- init ----------------
    if (tid < NBUF) flags[tid] = 0;
    if (tid < 4) done[tid] = 0;
    if (tid == 0) cbar = 0;
    for (int idx = tid; idx < KTOT * 16; idx += NTHR) {
        int kk = idx >> 4, cc = idx & 15;
        int col = (cc >> 2) * 512 + hs * 4 + (cc & 3);
        float v;
        if (kk < 512)      v = Wh[kk * 2048 + col];
        else if (kk < 592) v = Wx[(3 + kk - 512) * 2048 + col];
        else               v = Wx[(kk - 592) * 2048 + col];
        Wl[idx] = v;
    }
    for (int i = tid; i < 256; i += NTHR) cst[i] = 0.f;
    if (tid < M_) kapl[tid] = 0.f;
    if (tid < 30) bdl[tid] = bd[tid];
    if (tid < 16) biasl[tid] = bias[(tid >> 2) * 512 + hs * 4 + (tid & 3)];
    {   // zero h ping-pong + w carry
        int tot = 2 * 2 * H_ * HB + 2 * N_ * HB;
        for (int i = bid * NTHR + tid; i < tot; i += NBLK * NTHR) {
            if (i < 2 * 2 * H_ * HB) hbuf[i] = 0.f;
            else wbufT[i - 2 * 2 * H_ * HB] = 0.f;
        }
    }
    // WdT[col*512+j] = Wd[j*30+col]
    for (int i = bid * NTHR + tid; i < 30 * 512; i += NBLK * NTHR) {
        int col = i >> 9, j = i & 511;
        WdT[i] = Wd[j * 30 + col];
    }
    if (transT) {  // transT[b][n][u]
        for (int i = bid * NTHR + tid; i < B_ * 10240; i += NBLK * NTHR) {
            int b = i / 10240, r = i % 10240;
            int n = r >> 7, u = r & 127;
            transT[i] = trans[(size_t)b * 10240 + u * 80 + n];
        }
    }
    __syncthreads();
    if (tid == 0) {
        __threadfence();
        atomicAdd(&cnt[512], 1u);
        while (__hip_atomic_load(&cnt[512], __ATOMIC_RELAXED, __HIP_MEMORY_SCOPE_AGENT) < (unsigned)NBLK)
            __builtin_amdgcn_s_sleep(1);
        __threadfence();
    }
    __syncthreads();

    const bool isB = (hs & 1) == 0;
    const int  bB  = half * HB + (hs >> 1);

    // =============== consumers: waves 0-3 ===============
    if (w8 < 4) {
        const int rw   = w8;            // col group (gate)
        const int bg4  = lane & 15;
        const int ks   = lane >> 4;     // K-split 4
        const int cg4  = rw * 4;
        const int bg44 = bg4 * 4;
        unsigned cphase = 0;
        unsigned Cg = 0;

        for (int t = 0; t < T_; ++t) {
            float* hW = hbuf + (((t + 1) & 1) * 2 + half) * (H_ * HB);
            float acc[4][4];
            #pragma unroll
            for (int a = 0; a < 4; ++a)
                #pragma unroll
                for (int b2 = 0; b2 < 4; ++b2) acc[a][b2] = 0.f;

            for (int c = 0; c < 19; ++c, ++Cg) {
                int s = (int)(Cg % NBUF);
                unsigned want = Cg + 1;
                while (__hip_atomic_load(&flags[s], __ATOMIC_ACQUIRE, __HIP_MEMORY_SCOPE_WORKGROUP) < want)
                    __builtin_amdgcn_s_sleep(1);
                const float* ib = bufs + s * 2048;
                const float* wl = Wl + c * 32 * 16;
                if (c < 18) {
                    #pragma unroll
                    for (int i = 0; i < 8; ++i) {
                        int k = 4 * i + ks;
                        float4 iv = *(const float4*)(ib + k * 64 + bg44);
                        float4 wv = *(const float4*)(wl + k * 16 + cg4);
                        acc[0][0] = fmaf(iv.x, wv.x, acc[0][0]); acc[0][1] = fmaf(iv.x, wv.y, acc[0][1]);
                        acc[0][2] = fmaf(iv.x, wv.z, acc[0][2]); acc[0][3] = fmaf(iv.x, wv.w, acc[0][3]);
                        acc[1][0] = fmaf(iv.y, wv.x, acc[1][0]); acc[1][1] = fmaf(iv.y, wv.y, acc[1][1]);
                        acc[1][2] = fmaf(iv.y, wv.z, acc[1][2]); acc[1][3] = fmaf(iv.y, wv.w, acc[1][3]);
                        acc[2][0] = fmaf(iv.z, wv.x, acc[2][0]); acc[2][1] = fmaf(iv.z, wv.y, acc[2][1]);
                        acc[2][2] = fmaf(iv.z, wv.z, acc[2][2]); acc[2][3] = fmaf(iv.z, wv.w, acc[2][3]);
                        acc[3][0] = fmaf(iv.w, wv.x, acc[3][0]); acc[3][1] = fmaf(iv.w, wv.y, acc[3][1]);
                        acc[3][2] = fmaf(iv.w, wv.z, acc[3][2]); acc[3][3] = fmaf(iv.w, wv.w, acc[3][3]);
                    }
                } else {
                    for (int i = 0; i < 5; ++i) {
                        int k = 4 * i + ks;
                        if (k < 19) {
                            float4 iv = *(const float4*)(ib + k * 64 + bg44);
                            float4 wv = *(const float4*)(wl + k * 16 + cg4);
                            acc[0][0] = fmaf(iv.x, wv.x, acc[0][0]); acc[0][1] = fmaf(iv.x, wv.y, acc[0][1]);
                            acc[0][2] = fmaf(iv.x, wv.z, acc[0][2]); acc[0][3] = fmaf(iv.x, wv.w, acc[0][3]);
                            acc[1][0] = fmaf(iv.y, wv.x, acc[1][0]); acc[1][1] = fmaf(iv.y, wv.y, acc[1][1]);
                            acc[1][2] = fmaf(iv.y, wv.z, acc[1][2]); acc[1][3] = fmaf(iv.y, wv.w, acc[1][3]);
                            acc[2][0] = fmaf(iv.z, wv.x, acc[2][0]); acc[2][1] = fmaf(iv.z, wv.y, acc[2][1]);
                            acc[2][2] = fmaf(iv.z, wv.z, acc[2][2]); acc[2][3] = fmaf(iv.z, wv.w, acc[2][3]);
                            acc[3][0] = fmaf(iv.w, wv.x, acc[3][0]); acc[3][1] = fmaf(iv.w, wv.y, acc[3][1]);
                            acc[3][2] = fmaf(iv.w, wv.z, acc[3][2]); acc[3][3] = fmaf(iv.w, wv.w, acc[3][3]);
                        }
                    }
                }
                if (lane == 0)
                    __hip_atomic_store(&done[rw], want, __ATOMIC_RELEASE, __HIP_MEMORY_SCOPE_WORKGROUP);
            }

            // cross-K reduce + z stash (stride 20, float4-aligned)
            #pragma unroll
            for (int bb = 0; bb < 4; ++bb) {
                #pragma unroll
                for (int cc2 = 0; cc2 < 4; ++cc2) {
                    float v = acc[bb][cc2];
                    v += __shfl_xor(v, 16, 64);
                    v += __shfl_xor(v, 32, 64);
                    acc[bb][cc2] = v;
                }
                if (ks == 0)
                    *(float4*)&zbuf[(bg44 + bb) * 20 + cg4] =
                        make_float4(acc[bb][0], acc[bb][1], acc[bb][2], acc[bb][3]);
            }
            // consumer barrier 1 (z ready)
            ++cphase;
            if (lane == 0) __hip_atomic_fetch_add(&cbar, 1u, __ATOMIC_RELEASE, __HIP_MEMORY_SCOPE_WORKGROUP);
            while (__hip_atomic_load(&cbar, __ATOMIC_ACQUIRE, __HIP_MEMORY_SCOPE_WORKGROUP) < 4u * cphase)
                __builtin_amdgcn_s_sleep(0);

            // LSTM pointwise: thread = (b, jl)
            {
                int b = tid & 63, jl = w8;   // w8 = tid>>6
                float zi = zbuf[b * 20 + 0  + jl] + biasl[0  + jl];
                float zf = zbuf[b * 20 + 4  + jl] + biasl[4  + jl];
                float zg = zbuf[b * 20 + 8  + jl] + biasl[8  + jl];
                float zo = zbuf[b * 20 + 12 + jl] + biasl[12 + jl];
                float co = cst[b * 4 + jl];
                float si = 1.f / (1.f + expf(-zi));
                float sf = 1.f / (1.f + expf(-zf));
                float so = 1.f / (1.f + expf(-zo));
                float cn = sf * co + si * tanhf(zg);
                float hn = so * tanhf(cn);
                cst[b * 4 + jl] = cn;
                int colb = hs * 4 + jl;
                __hip_atomic_store(&hW[colb * 64 + b], hn, __ATOMIC_RELAXED, __HIP_MEMORY_SCOPE_AGENT);
                __hip_atomic_store(&hT[(size_t)(half * HB + b) * 512 + colb], hn,
                                   __ATOMIC_RELAXED, __HIP_MEMORY_SCOPE_AGENT);
            }
            __threadfence();   // per-wave: drain stores to coherence point
            // consumer barrier 2 (all waves' h flushed)
            ++cphase;
            if (lane == 0) __hip_atomic_fetch_add(&cbar, 1u, __ATOMIC_RELEASE, __HIP_MEMORY_SCOPE_WORKGROUP);
            while (__hip_atomic_load(&cbar, __ATOMIC_ACQUIRE, __HIP_MEMORY_SCOPE_WORKGROUP) < 4u * cphase)
                __builtin_amdgcn_s_sleep(0);
            if (tid == 0) atomicAdd(&hcnt[(bid & 7) * 16], 1u);   // release h_t
        }
    }
    // =============== stagers: waves 4-6 ===============
    else if (w8 < 7) {
        const int p = w8 - 4;
        for (int t = 0; t < T_; ++t) {
            const float* hR = hbuf + ((t & 1) * 2 + half) * (H_ * HB);
            wait_sum8(hcnt, 128u * (unsigned)t);
            __threadfence();   // invalidate caches before reading fresh h
            // h chunks: c % 3 == p, c < 16
            for (int c = p; c < 16; c += 3) {
                unsigned CgS = (unsigned)t * 19u + (unsigned)c;
                if (CgS >= NBUF) {
                    unsigned need = CgS - (NBUF - 1);
                    while (true) {
                        unsigned m0 = __hip_atomic_load(&done[0], __ATOMIC_RELAXED, __HIP_MEMORY_SCOPE_WORKGROUP);
                        unsigned m1 = __hip_atomic_load(&done[1], __ATOMIC_RELAXED, __HIP_MEMORY_SCOPE_WORKGROUP);
                        unsigned m2 = __hip_atomic_load(&done[2], __ATOMIC_RELAXED, __HIP_MEMORY_SCOPE_WORKGROUP);
                        unsigned m3 = __hip_atomic_load(&done[3], __ATOMIC_RELAXED, __HIP_MEMORY_SCOPE_WORKGROUP);
                        unsigned m = min(min(m0, m1), min(m2, m3));
                        if (m >= need) break;
                        __builtin_amdgcn_s_sleep(1);
                    }
                }
                float* dst = bufs + (CgS % NBUF) * 2048;
                const float* src = hR + c * 2048;
                #pragma unroll
                for (int i = 0; i < 8; ++i)
                    GLOAD16(src + i * 256 + lane * 4, dst + i * 256);
                __threadfence_block();   // wait own vmcnt: LDS data landed
                if (lane == 0)
                    __hip_atomic_store(&flags[CgS % NBUF], CgS + 1u, __ATOMIC_RELAXED, __HIP_MEMORY_SCOPE_WORKGROUP);
            }
            // w chunk: c = 16 + p
            wait_sum8(wcnt, 64u * (unsigned)t);
            __threadfence();
            {
                int c = 16 + p;
                unsigned CgS = (unsigned)t * 19u + (unsigned)c;
                unsigned need = CgS - (NBUF - 1);
                while (true) {
                    unsigned m0 = __hip_atomic_load(&done[0], __ATOMIC_RELAXED, __HIP_MEMORY_SCOPE_WORKGROUP);
                    unsigned m1 = __hip_atomic_load(&done[1], __ATOMIC_RELAXED, __HIP_MEMORY_SCOPE_WORKGROUP);
                    unsigned m2 = __hip_atomic_load(&done[2], __ATOMIC_RELAXED, __HIP_MEMORY_SCOPE_WORKGROUP);
                    unsigned m3 = __hip_atomic_load(&done[3], __ATOMIC_RELAXED, __HIP_MEMORY_SCOPE_WORKGROUP);
                    unsigned m = min(min(m0, m1), min(m2, m3));
                    if (m >= need) break;
                    __builtin_amdgcn_s_sleep(1);
                }
                float* dst = bufs + (CgS % NBUF) * 2048;
                if (p < 2) {
                    const float* src = wT_half + p * 2048;
                    #pragma unroll
                    for (int i = 0; i < 8; ++i)
                        GLOAD16(src + i * 256 + lane * 4, dst + i * 256);
                } else {
                    const float* src = wT_half + 4096;   // w rows 64..79
                    #pragma unroll
                    for (int i = 0; i < 4; ++i)
                        GLOAD16(src + i * 256 + lane * 4, dst + i * 256);
                    #pragma unroll
                    for (int r = 0; r < 3; ++r)
                        dst[(16 + r) * 64 + lane] =
                            strokes[(size_t)(half * HB + lane) * (T_ * 3) + t * 3 + r];
                }
                __threadfence_block();
                if (lane == 0)
                    __hip_atomic_store(&flags[CgS % NBUF], CgS + 1u, __ATOMIC_RELAXED, __HIP_MEMORY_SCOPE_WORKGROUP);
            }
        }
    }
    // =============== attention: wave 7, B-blocks only ===============
    else if (isB) {
        for (int t = 0; t < T_; ++t) {
            wait_sum8(hcnt, 128u * (unsigned)(t + 1));
            __threadfence();
            float* op = out + ((size_t)bB * T_ + t) * 593;
            // h column -> regs + LDS
            const float4* hp4 = (const float4*)(hT + (size_t)bB * 512);
            float4 ha = hp4[lane * 2], hb2 = hp4[lane * 2 + 1];
            *(float4*)&hcol[lane * 8] = ha;
            *(float4*)&hcol[lane * 8 + 4] = hb2;
            __threadfence_block();
            // h -> out (coalesced, nontemporal)
            #pragma unroll
            for (int k = 0; k < 8; ++k)
                __builtin_nontemporal_store(hcol[k * 64 + lane], op + k * 64 + lane);
            // y = h @ Wd (lanes 0-29, dense WdT rows)
            if (lane < 30) {
                const float4* wdp = (const float4*)(WdT + lane * 512);
                float s0 = 0.f, s1 = 0.f;
                #pragma unroll 8
                for (int j4 = 0; j4 < 128; j4 += 2) {
                    float4 hv = *(const float4*)&hcol[j4 * 4];
                    float4 wv = wdp[j4];
                    s0 = fmaf(hv.x, wv.x, s0); s0 = fmaf(hv.y, wv.y, s0);
                    s0 = fmaf(hv.z, wv.z, s0); s0 = fmaf(hv.w, wv.w, s0);
                    float4 hv2 = *(const float4*)&hcol[j4 * 4 + 4];
                    float4 wv2 = wdp[j4 + 1];
                    s1 = fmaf(hv2.x, wv2.x, s1); s1 = fmaf(hv2.y, wv2.y, s1);
                    s1 = fmaf(hv2.z, wv2.z, s1); s1 = fmaf(hv2.w, wv2.w, s1);
                }
                yl[lane] = expf(s0 + s1 + bdl[lane]);
            }
            __threadfence_block();
            if (lane >= 20 && lane < 30) kapl[lane - 20] += yl[lane];
            __threadfence_block();
            // wf[u] for u = lane, lane+64, 128
            float w0 = 0.f, w1 = 0.f, w2 = 0.f;
            {
                float u0 = (float)lane, u1 = (float)(lane + 64);
                #pragma unroll
                for (int m = 0; m < M_; ++m) {
                    float a = yl[m], b3 = yl[10 + m], k2 = kapl[m];
                    float d0 = k2 - u0, d1 = k2 - u1, d2 = k2 - 128.f;
                    w0 = fmaf(a, expf(-b3 * d0 * d0), w0);
                    w1 = fmaf(a, expf(-b3 * d1 * d1), w1);
                    w2 = fmaf(a, expf(-b3 * d2 * d2), w2);
                }
                wfl[lane] = w0; wfl[lane + 64] = w1;
                if (lane == 0) wfl[128] = w2;
            }
            __threadfence_block();
            // argmax, np first-max semantics
            {
                float bv; int biv;
                if (w1 > w0) { bv = w1; biv = lane + 64; } else { bv = w0; biv = lane; }
                #pragma unroll
                for (int off = 32; off >= 1; off >>= 1) {
                    float ov = __shfl_xor(bv, off, 64);
                    int   oi = __shfl_xor(biv, off, 64);
                    if (ov > bv || (ov == bv && oi < biv)) { bv = ov; biv = oi; }
                }
                if (w2 > bv) biv = 128;
                if (lane == 0) __builtin_nontemporal_store((float)biv, op + 592);
            }
            // w = wfull[:128] @ trans[b]
            #pragma unroll
            for (int pass = 0; pass < 2; ++pass) {
                int n = pass * 64 + lane;
                if (n < N_) {
                    float s = 0.f;
                    if (transT) {
                        const float4* tp4 = (const float4*)(transT + (size_t)bB * 10240 + n * 128);
                        #pragma unroll 8
                        for (int u4 = 0; u4 < 32; ++u4) {
                            float4 wv = *(const float4*)&wfl[u4 * 4];
                            float4 tv = tp4[u4];
                            s = fmaf(wv.x, tv.x, s); s = fmaf(wv.y, tv.y, s);
                            s = fmaf(wv.z, tv.z, s); s = fmaf(wv.w, tv.w, s);
                        }
                    } else {
                        const float* tp = trans + (size_t)bB * (U_ * N_) + n;
                        #pragma unroll 8
                        for (int u = 0; u < U_; ++u) s = fmaf(wfl[u], tp[u * N_], s);
                    }
                    __builtin_nontemporal_store(s, op + 512 + n);
                    __hip_atomic_store(&wT_half[n * 64 + (bB & 63)], s,
                                       __ATOMIC_RELAXED, __HIP_MEMORY_SCOPE_AGENT);
                }
            }
            __threadfence();
            if (lane == 0) atomicAdd(&wcnt[((bid >> 1) & 7) * 16], 1u);   // release w_t
        }
    }
}

extern "C" void kernel_launch(void* const* d_in, const int* in_sizes, int n_in,
                              void* d_out, int out_size, void* d_ws, size_t ws_size,
                              hipStream_t stream) {
    const float* strokes = (const float*)d_in[0];
    const float* trans   = (const float*)d_in[1];
    // d_in[2] = enumerated (arange, recomputed in-kernel)
    const float* Wx      = (const float*)d_in[3];
    const float* Wh      = (const float*)d_in[4];
    const float* bias    = (const float*)d_in[5];
    const float* Wd      = (const float*)d_in[6];
    const float* bd      = (const float*)d_in[7];
    float* out = (float*)d_out;

    unsigned* cnt = (unsigned*)d_ws;                       // 4 KB counters
    float* hbuf  = (float*)((char*)d_ws + 4096);           // [par][half][512][64] 512 KB
    float* wbufT = hbuf + 2 * 2 * H_ * HB;                 // [half][80][64] 40 KB
    float* hT    = wbufT + 2 * N_ * HB;                    // [128][512] 256 KB
    float* WdT   = hT + B_ * H_;                           // [30][512] 60 KB
    float* transT = WdT + 30 * 512;                        // [128][80][128] 5 MB (optional)
    size_t need_base = 4096 + (size_t)(2 * 2 * H_ * HB + 2 * N_ * HB + B_ * H_ + 30 * 512) * 4;
    size_t need_full = need_base + (size_t)B_ * 10240 * 4;
    if (ws_size < need_full) transT = nullptr;

    static int attr_set = 0;
    hipFuncSetAttribute((const void*)rnn_kernel,
                        hipFuncAttributeMaxDynamicSharedMemorySize, SMEM_BYTES);
    (void)attr_set;

    hipMemsetAsync(d_ws, 0, 4096, stream);                 // reset counters (ws is poisoned)
    hipLaunchKernelGGL(rnn_kernel, dim3(NBLK), dim3(NTHR), SMEM_BYTES, stream,
                       strokes, trans, Wx, Wh, bias, Wd, bd, out, hbuf, wbufT, hT,
                       WdT, transT, cnt);
}